// Round 1
// baseline (429.744 us; speedup 1.0000x reference)
//
#include <hip/hip_runtime.h>

// HashEmbedding: out[b,l,:] = [ sum_h W[hash_table[word,h],:] * P[word,h]  (64 floats),
//                               P[hash_table[word,0],0], P[hash_table[word,1],1] ]
// B=16384, L=50, NUM_HASH=2, EMBED=64 -> 819200 tokens x 66 floats out.

#define TOKENS (16384 * 50)
#define EMBED 64
#define OUT_STRIDE 66

__global__ __launch_bounds__(256) void HashEmbedding_32401233281223_kernel(
    const int*   __restrict__ words,      // [TOKENS]
    const int*   __restrict__ hash_table, // [NUM_WORDS, 2]
    const float* __restrict__ W,          // [NUM_BUCKETS, 64]
    const float* __restrict__ P,          // [NUM_WORDS, 2]
    float*       __restrict__ out)        // [TOKENS, 66]
{
    // One wave (64 lanes) per token. 256-thread block = 4 tokens.
    const int token = (int)((blockIdx.x * blockDim.x + threadIdx.x) >> 6);
    const int lane  = threadIdx.x & 63;
    if (token >= TOKENS) return;

    // Wave-uniform scalars: same-address loads broadcast across the wave.
    const int word = words[token];
    const int h0 = hash_table[word * 2 + 0];
    const int h1 = hash_table[word * 2 + 1];
    const float p0 = P[word * 2 + 0];
    const float p1 = P[word * 2 + 1];

    // Coalesced row gathers: lane e reads element e of each 64-float W row.
    const float w0 = W[(size_t)h0 * EMBED + lane];
    const float w1 = W[(size_t)h1 * EMBED + lane];
    const float e  = fmaf(w0, p0, w1 * p1);

    float* o = out + (size_t)token * OUT_STRIDE;
    o[lane] = e;                          // 64 contiguous floats
    if (lane == 0) o[EMBED + 0] = P[h0 * 2 + 0];  // pvals: P indexed by BUCKET id
    if (lane == 1) o[EMBED + 1] = P[h1 * 2 + 1];
}

extern "C" void kernel_launch(void* const* d_in, const int* in_sizes, int n_in,
                              void* d_out, int out_size, void* d_ws, size_t ws_size,
                              hipStream_t stream) {
    const int*   words      = (const int*)d_in[0];
    const int*   hash_table = (const int*)d_in[1];
    const float* W          = (const float*)d_in[2];
    const float* P          = (const float*)d_in[3];
    float*       out        = (float*)d_out;

    // 4 tokens per 256-thread block (one wave each).
    const int blocks = (TOKENS + 3) / 4;
    HashEmbedding_32401233281223_kernel<<<blocks, 256, 0, stream>>>(
        words, hash_table, W, P, out);
}

// Round 2
// 332.604 us; speedup vs baseline: 1.2921x; 1.2921x over previous
//
#include <hip/hip_runtime.h>

// HashEmbedding: out[t,:] = [ sum_h W[ht[word,h],:] * P[word,h]  (64 floats),
//                             P[ht[word,0],0], P[ht[word,1],1] ]
// TOKENS=819200, EMBED=64, H=2, out row = 66 floats (264 B).
//
// R1 design: 32 lanes per token (float2/lane = 256 B W row), 2 groups/wave,
// 4-token unroll per group => 8 tokens/wave. Converts the 3-deep dependent
// gather chain (word -> hash/P -> W/pvals) from per-token to per-8-tokens,
// giving ~8x the memory-level parallelism per wave. Nontemporal stores keep
// the 211 MB output stream from thrashing the 4 MB per-XCD L2 that the
// W (25.6 MB) / hash_table (8 MB) / P (8 MB) gathers need.

#define TOKENS (16384 * 50)
#define EMBED 64
#define OUT_STRIDE 66
#define TOK_PER_WAVE 8
#define TOK_PER_BLOCK 32  // 4 waves * 8

typedef float f2 __attribute__((ext_vector_type(2)));
typedef int   i2 __attribute__((ext_vector_type(2)));

__global__ __launch_bounds__(256) void HashEmbedding_32401233281223_kernel(
    const int*   __restrict__ words, // [TOKENS]
    const int*   __restrict__ ht,    // [NUM_WORDS,2]
    const float* __restrict__ W,     // [NUM_BUCKETS,64]
    const float* __restrict__ P,     // [NUM_WORDS,2] (also indexed by bucket for pvals)
    float*       __restrict__ out)   // [TOKENS,66]
{
    const int tid  = blockIdx.x * 256 + threadIdx.x;
    const int wave = tid >> 6;
    const int lane = threadIdx.x & 63;
    const int grp  = lane >> 5;   // two 32-lane token-groups per wave
    const int gl   = lane & 31;   // lane within group; covers W row as float2

    const int t0 = wave * TOK_PER_WAVE + grp * 4;  // exact fit: TOKENS % 8 == 0

    // ---- Level 0: word ids (broadcast; 4 consecutive ids share one line) ----
    const int w0 = words[t0 + 0];
    const int w1 = words[t0 + 1];
    const int w2 = words[t0 + 2];
    const int w3 = words[t0 + 3];

    // ---- Level 1: hash pairs + per-word P pairs (8 independent loads) ----
    const i2* ht2 = (const i2*)ht;
    const f2* P2  = (const f2*)P;
    const i2 h0 = ht2[w0];
    const i2 h1 = ht2[w1];
    const i2 h2 = ht2[w2];
    const i2 h3 = ht2[w3];
    const f2 p0 = P2[w0];
    const f2 p1 = P2[w1];
    const f2 p2 = P2[w2];
    const f2 p3 = P2[w3];

    // ---- Level 2: W rows (8 independent float2 gathers) + pvals ----
    const f2* W2 = (const f2*)W;  // row r = W2[r*32 + gl]
    const f2 a0 = W2[(size_t)h0.x * 32 + gl];
    const f2 b0 = W2[(size_t)h0.y * 32 + gl];
    const f2 a1 = W2[(size_t)h1.x * 32 + gl];
    const f2 b1 = W2[(size_t)h1.y * 32 + gl];
    const f2 a2 = W2[(size_t)h2.x * 32 + gl];
    const f2 b2 = W2[(size_t)h2.y * 32 + gl];
    const f2 a3 = W2[(size_t)h3.x * 32 + gl];
    const f2 b3 = W2[(size_t)h3.y * 32 + gl];
    // pvals: P indexed by BUCKET id, column = hash index (broadcast loads, L2-resident 800KB)
    const f2 q0 = { P[2 * h0.x + 0], P[2 * h0.y + 1] };
    const f2 q1 = { P[2 * h1.x + 0], P[2 * h1.y + 1] };
    const f2 q2 = { P[2 * h2.x + 0], P[2 * h2.y + 1] };
    const f2 q3 = { P[2 * h3.x + 0], P[2 * h3.y + 1] };

    // ---- Compute ----
    const f2 e0 = a0 * p0.x + b0 * p0.y;
    const f2 e1 = a1 * p1.x + b1 * p1.y;
    const f2 e2 = a2 * p2.x + b2 * p2.y;
    const f2 e3 = a3 * p3.x + b3 * p3.y;

    // ---- Stores (nontemporal: output is write-once, keep it out of L2) ----
    // out row base = 264*t bytes -> 8-byte aligned for every t, so f2 is legal.
    float* o0 = out + (size_t)(t0 + 0) * OUT_STRIDE;
    float* o1 = out + (size_t)(t0 + 1) * OUT_STRIDE;
    float* o2 = out + (size_t)(t0 + 2) * OUT_STRIDE;
    float* o3 = out + (size_t)(t0 + 3) * OUT_STRIDE;
    __builtin_nontemporal_store(e0, (f2*)o0 + gl);
    __builtin_nontemporal_store(e1, (f2*)o1 + gl);
    __builtin_nontemporal_store(e2, (f2*)o2 + gl);
    __builtin_nontemporal_store(e3, (f2*)o3 + gl);
    if (gl == 0) {
        __builtin_nontemporal_store(q0, (f2*)(o0 + EMBED));
        __builtin_nontemporal_store(q1, (f2*)(o1 + EMBED));
        __builtin_nontemporal_store(q2, (f2*)(o2 + EMBED));
        __builtin_nontemporal_store(q3, (f2*)(o3 + EMBED));
    }
}

extern "C" void kernel_launch(void* const* d_in, const int* in_sizes, int n_in,
                              void* d_out, int out_size, void* d_ws, size_t ws_size,
                              hipStream_t stream) {
    const int*   words      = (const int*)d_in[0];
    const int*   hash_table = (const int*)d_in[1];
    const float* W          = (const float*)d_in[2];
    const float* P          = (const float*)d_in[3];
    float*       out        = (float*)d_out;

    const int blocks = TOKENS / TOK_PER_BLOCK;  // 25600
    HashEmbedding_32401233281223_kernel<<<blocks, 256, 0, stream>>>(
        words, hash_table, W, P, out);
}